// Round 10
// baseline (50.985 us; speedup 1.0000x reference)
//
#include <hip/hip_runtime.h>
#include <math.h>

// x = (8, 3, 1024, 1024) f32, out = (8, 3, 1024, 1024) f32
constexpr int H = 1024, W = 1024, B = 8;
constexpr int NPIX = H * W;

typedef float f32x4 __attribute__((ext_vector_type(4)));   // native vec for NT stores

// ---------------- fused cooperative path ----------------
constexpr int FR    = 16;              // rows per block
constexpr int GPB   = H / FR;          // 64 row-groups (blocks) per image
constexpr int FGRID = B * GPB;         // 512 blocks = 2/CU on 256 CUs

__device__ __forceinline__ void gload16(const float* g, float* l) {
    __builtin_amdgcn_global_load_lds(
        (const __attribute__((address_space(1))) void*)g,
        (__attribute__((address_space(3))) void*)l, 16, 0, 0);
}
__device__ __forceinline__ float grayat(const float* __restrict__ xb, int r, int c) {
    const float* p = xb + (size_t)r * W + c;
    return 0.3f * p[0] + 0.59f * p[NPIX] + 0.11f * p[2 * NPIX];
}
__device__ __forceinline__ void nt_store4(float* p, float x, float y, float z, float w) {
    f32x4 v = {x, y, z, w};
    __builtin_nontemporal_store(v, reinterpret_cast<f32x4*>(p));
}

union PackF2 { float2 f; unsigned long long u; };

// One fused kernel. Phase A: per-wave pipelined staging (5-slot LDS ring,
// counted vmcnt(9) = 3 rows in flight, no barriers) -> gray -> stencil -> t in
// 16 float4 regs + per-block partial. PER-IMAGE sync: release-add arrival
// counter, tid0 acquire-spin until the image's 64 partials landed (coop launch
// guarantees co-residency). Phase B: butterfly-reduce 64 partials (one/lane),
// normalize regs, write 3 replicated channels with NON-TEMPORAL stores.
__global__ __launch_bounds__(256, 2)
void ltpe_fused(const float* __restrict__ x, float* __restrict__ out,
                float2* __restrict__ part, unsigned* __restrict__ cnt)
{
    __shared__ float lds[4][5][3][256];   // per-wave ring: 5 slots x 3 ch x 256 cols
    __shared__ float2 wred[4];

    const int blk  = blockIdx.x;
    const int b    = blk & 7;             // image pinned to XCD (round-robin dispatch)
    const int g    = blk >> 3;            // row-group 0..63
    const int r0   = g * FR;
    const int tid  = threadIdx.x;
    const int w    = tid >> 6;
    const int lane = tid & 63;
    const int c    = tid << 2;            // global column quad
    const float* xb = x + (size_t)b * 3 * NPIX;
    float (*ldsw)[3][256] = lds[w];       // this wave's private ring

    constexpr float w0 = 1.f/255.f,  w1 = 2.f/255.f,  w2 = 4.f/255.f,  w3 = 8.f/255.f,
                    w4 = 16.f/255.f, w5 = 32.f/255.f, w6 = 64.f/255.f, w7 = 128.f/255.f;

    // Prologue: edge-lane horizontal-halo gray values into registers, then DRAIN
    // vmcnt so the steady-state loop's counted waits are exact.
    float pL[FR + 2], pR[FR + 2];
    #pragma unroll
    for (int i = 0; i < FR + 2; ++i) { pL[i] = 0.f; pR[i] = 0.f; }
    if (lane == 0 && c > 0) {
        #pragma unroll
        for (int i = 0; i < FR + 2; ++i) {
            const int rr = r0 - 1 + i;
            if ((unsigned)rr < (unsigned)H) pL[i] = grayat(xb, rr, c - 1);
        }
    }
    if (lane == 63 && c + 4 < W) {
        #pragma unroll
        for (int i = 0; i < FR + 2; ++i) {
            const int rr = r0 - 1 + i;
            if ((unsigned)rr < (unsigned)H) pR[i] = grayat(xb, rr, c + 4);
        }
    }
    asm volatile("s_waitcnt vmcnt(0)" ::: "memory");
    __builtin_amdgcn_sched_barrier(0);

    // Stage row-offset `off` (row r0-1+off, CLAMPED so every block issues the
    // same gload count; garbage rows are zeroed at gray time) into ring slot.
    auto stage = [&](int off, int slot) {
        int rr = r0 - 1 + off;
        rr = rr < 0 ? 0 : (rr > H - 1 ? H - 1 : rr);
        const float* gp = xb + (size_t)rr * W + (w << 8) + (lane << 2);
        gload16(gp,            &ldsw[slot][0][0]);
        gload16(gp + NPIX,     &ldsw[slot][1][0]);
        gload16(gp + 2*NPIX,   &ldsw[slot][2][0]);
    };

    // Gray (6-wide) for row-offset `off` from ring slot.
    auto grayc = [&](int off, int slot, float (&d)[6]) {
        const bool rok = (unsigned)(r0 - 1 + off) < (unsigned)H;
        const float4 a = *reinterpret_cast<const float4*>(&ldsw[slot][0][lane << 2]);
        const float4 e = *reinterpret_cast<const float4*>(&ldsw[slot][1][lane << 2]);
        const float4 f = *reinterpret_cast<const float4*>(&ldsw[slot][2][lane << 2]);
        float g1 = 0.3f*a.x + 0.59f*e.x + 0.11f*f.x;
        float g2 = 0.3f*a.y + 0.59f*e.y + 0.11f*f.y;
        float g3 = 0.3f*a.z + 0.59f*e.z + 0.11f*f.z;
        float g4 = 0.3f*a.w + 0.59f*e.w + 0.11f*f.w;
        float glv = __shfl_up(g4, 1);
        float grv = __shfl_down(g1, 1);
        if (lane == 0)  glv = pL[off];
        if (lane == 63) grv = pR[off];
        if (!rok) { g1 = g2 = g3 = g4 = glv = grv = 0.f; }   // zero-pad row
        d[0]=glv; d[1]=g1; d[2]=g2; d[3]=g3; d[4]=g4; d[5]=grv;
    };

    float gr6[3][6];
    float4 tq[FR];                        // un-normalized t, lives in VGPRs
    float s = 0.f, ss = 0.f;

    // Pipeline prologue: offsets 0..4 staged (15 gloads); rows 0,1 resident
    // after vmcnt(9).
    stage(0, 0); stage(1, 1); stage(2, 2); stage(3, 3); stage(4, 4);
    asm volatile("s_waitcnt vmcnt(9)" ::: "memory");
    __builtin_amdgcn_sched_barrier(0);
    grayc(0, 0, gr6[0]);
    grayc(1, 1, gr6[1]);

    // Step I: issue offset I+5 (3 gloads), wait so offset I+2 is resident
    // (outstanding = offsets I+3..I+5 = 9), gray(I+2), stencil output row r0+I.
#define LTPE_STEP(I, WAITSTR)                                                  \
    {                                                                          \
        if ((I) + 5 <= FR + 1) stage((I) + 5, ((I) + 5) % 5);                  \
        asm volatile(WAITSTR ::: "memory");                                    \
        __builtin_amdgcn_sched_barrier(0);                                     \
        grayc((I) + 2, ((I) + 2) % 5, gr6[((I) + 2) % 3]);                     \
        const float (&up)[6] = gr6[(I) % 3];                                   \
        const float (&mi)[6] = gr6[((I) + 1) % 3];                             \
        const float (&dn)[6] = gr6[((I) + 2) % 3];                             \
        float tv[4];                                                           \
        _Pragma("unroll")                                                      \
        for (int kk = 0; kk < 4; ++kk) {                                       \
            float sv = w0 * mi[kk];                                            \
            sv = fmaf(w1, dn[kk],     sv);                                     \
            sv = fmaf(w2, dn[kk + 1], sv);                                     \
            sv = fmaf(w3, dn[kk + 2], sv);                                     \
            sv = fmaf(w4, mi[kk + 2], sv);                                     \
            sv = fmaf(w5, up[kk + 2], sv);                                     \
            sv = fmaf(w6, up[kk + 1], sv);                                     \
            sv = fmaf(w7, up[kk],     sv);                                     \
            tv[kk] = 0.5f * mi[kk + 1] + 0.5f - 0.5f * sv;                     \
            s += tv[kk];                                                       \
            ss = fmaf(tv[kk], tv[kk], ss);                                     \
        }                                                                      \
        tq[I] = make_float4(tv[0], tv[1], tv[2], tv[3]);                       \
    }

    LTPE_STEP(0,  "s_waitcnt vmcnt(9)")
    LTPE_STEP(1,  "s_waitcnt vmcnt(9)")
    LTPE_STEP(2,  "s_waitcnt vmcnt(9)")
    LTPE_STEP(3,  "s_waitcnt vmcnt(9)")
    LTPE_STEP(4,  "s_waitcnt vmcnt(9)")
    LTPE_STEP(5,  "s_waitcnt vmcnt(9)")
    LTPE_STEP(6,  "s_waitcnt vmcnt(9)")
    LTPE_STEP(7,  "s_waitcnt vmcnt(9)")
    LTPE_STEP(8,  "s_waitcnt vmcnt(9)")
    LTPE_STEP(9,  "s_waitcnt vmcnt(9)")
    LTPE_STEP(10, "s_waitcnt vmcnt(9)")
    LTPE_STEP(11, "s_waitcnt vmcnt(9)")
    LTPE_STEP(12, "s_waitcnt vmcnt(9)")
    LTPE_STEP(13, "s_waitcnt vmcnt(6)")
    LTPE_STEP(14, "s_waitcnt vmcnt(3)")
    LTPE_STEP(15, "s_waitcnt vmcnt(0)")
#undef LTPE_STEP

    // Block reduce -> one fp32 partial pair per block.
    #pragma unroll
    for (int off = 32; off >= 1; off >>= 1) {
        s  += __shfl_down(s, off);
        ss += __shfl_down(ss, off);
    }
    if (lane == 0) wred[w] = make_float2(s, ss);
    __syncthreads();

    // Per-image sync: publish partial (agent-scope), release-add arrival
    // counter, tid0 acquire-spins until all GPB blocks of this image arrived.
    if (tid == 0) {
        float2 a0 = wred[0], a1 = wred[1], a2 = wred[2], a3 = wred[3];
        PackF2 pk;
        pk.f = make_float2(a0.x + a1.x + a2.x + a3.x,
                           a0.y + a1.y + a2.y + a3.y);
        __hip_atomic_store(
            reinterpret_cast<unsigned long long*>(&part[(size_t)b * GPB + g]),
            pk.u, __ATOMIC_RELAXED, __HIP_MEMORY_SCOPE_AGENT);
        __hip_atomic_fetch_add(&cnt[b], 1u, __ATOMIC_RELEASE,
                               __HIP_MEMORY_SCOPE_AGENT);
        while (__hip_atomic_load(&cnt[b], __ATOMIC_ACQUIRE,
                                 __HIP_MEMORY_SCOPE_AGENT) < (unsigned)GPB) {
            __builtin_amdgcn_s_sleep(1);
        }
    }
    __syncthreads();

    // Phase B: butterfly-reduce the image's 64 partials (one per lane) in double.
    PackF2 pv;
    pv.u = __hip_atomic_load(
        reinterpret_cast<const unsigned long long*>(&part[(size_t)b * GPB + lane]),
        __ATOMIC_RELAXED, __HIP_MEMORY_SCOPE_AGENT);
    double ds = (double)pv.f.x, dss = (double)pv.f.y;
    #pragma unroll
    for (int o = 1; o <= 32; o <<= 1) {
        ds  += __shfl_xor(ds, o);
        dss += __shfl_xor(dss, o);
    }
    const double n     = (double)NPIX;
    const double dmean = ds / n;
    const double dvar  = dss / n - dmean * dmean;
    const float mean = (float)dmean;
    const float rstd = (float)(1.0 / sqrt(dvar + 1e-5));

    // Non-temporal writes: out is never re-read; keep x resident in L3.
    float* ob = out + (size_t)b * 3 * NPIX + (size_t)r0 * W + c;
    #pragma unroll
    for (int i = 0; i < FR; ++i) {
        const float4 t4 = tq[i];
        const float yx = (t4.x - mean) * rstd;
        const float yy = (t4.y - mean) * rstd;
        const float yz = (t4.z - mean) * rstd;
        const float yw = (t4.w - mean) * rstd;
        float* p = ob + (size_t)i * W;
        nt_store4(p,            yx, yy, yz, yw);
        nt_store4(p + NPIX,     yx, yy, yz, yw);
        nt_store4(p + 2 * NPIX, yx, yy, yz, yw);
    }
}

// ---------------- fallback: proven round-6 two-kernel pipeline ----------------
constexpr int ROWS = 2;
constexpr int RG   = H / ROWS;          // 512

__global__ __launch_bounds__(256)
void ltpe_stage1(const float* __restrict__ x, float* __restrict__ out,
                 float2* __restrict__ part)
{
    __shared__ float lds[4][3][W];                // 48 KiB -> 3 blocks/CU
    const int b   = blockIdx.y;
    const int k   = blockIdx.x;
    const int kg  = ((k & 7) << 6) | (k >> 3);    // XCD-chunked bijective swizzle
    const int r0  = kg * ROWS;
    const int tid = threadIdx.x;
    const int w   = tid >> 6;
    const int l   = tid & 63;
    const int c   = tid << 2;
    const float* xb = x + (size_t)b * 3 * NPIX;

    #pragma unroll
    for (int s = 0; s < 4; ++s) {
        const int rr = r0 - 1 + s;
        if ((unsigned)rr < (unsigned)H) {
            #pragma unroll
            for (int ch = 0; ch < 3; ++ch) {
                const float* gp = xb + (size_t)ch * NPIX + (size_t)rr * W + (w << 8) + (l << 2);
                gload16(gp, &lds[s][ch][w << 8]);
            }
        } else {
            const float4 z = make_float4(0.f, 0.f, 0.f, 0.f);
            #pragma unroll
            for (int ch = 0; ch < 3; ++ch)
                *reinterpret_cast<float4*>(&lds[s][ch][c]) = z;
        }
    }
    __syncthreads();

    const int ql = (tid == 0)   ? 0   : tid - 1;
    const int qr = (tid == 255) ? 255 : tid + 1;
    float g6[4][6];
    #pragma unroll
    for (int s = 0; s < 4; ++s) {
        const float4 o0 = *reinterpret_cast<const float4*>(&lds[s][0][c]);
        const float4 o1 = *reinterpret_cast<const float4*>(&lds[s][1][c]);
        const float4 o2 = *reinterpret_cast<const float4*>(&lds[s][2][c]);
        const float4 l0 = *reinterpret_cast<const float4*>(&lds[s][0][ql << 2]);
        const float4 l1 = *reinterpret_cast<const float4*>(&lds[s][1][ql << 2]);
        const float4 l2 = *reinterpret_cast<const float4*>(&lds[s][2][ql << 2]);
        const float4 rq0 = *reinterpret_cast<const float4*>(&lds[s][0][qr << 2]);
        const float4 rq1 = *reinterpret_cast<const float4*>(&lds[s][1][qr << 2]);
        const float4 rq2 = *reinterpret_cast<const float4*>(&lds[s][2][qr << 2]);
        g6[s][1] = 0.3f * o0.x + 0.59f * o1.x + 0.11f * o2.x;
        g6[s][2] = 0.3f * o0.y + 0.59f * o1.y + 0.11f * o2.y;
        g6[s][3] = 0.3f * o0.z + 0.59f * o1.z + 0.11f * o2.z;
        g6[s][4] = 0.3f * o0.w + 0.59f * o1.w + 0.11f * o2.w;
        g6[s][0] = (tid == 0)   ? 0.f : 0.3f * l0.w  + 0.59f * l1.w  + 0.11f * l2.w;
        g6[s][5] = (tid == 255) ? 0.f : 0.3f * rq0.x + 0.59f * rq1.x + 0.11f * rq2.x;
    }

    constexpr float w0 = 1.f/255.f,  w1 = 2.f/255.f,  w2 = 4.f/255.f,  w3 = 8.f/255.f,
                    w4 = 16.f/255.f, w5 = 32.f/255.f, w6 = 64.f/255.f, w7 = 128.f/255.f;
    float s = 0.f, ss = 0.f;
    float* ob = out + (size_t)b * 3 * NPIX + (size_t)r0 * W + c;
    #pragma unroll
    for (int rr = 0; rr < ROWS; ++rr) {
        const float (&up)[6] = g6[rr];
        const float (&mi)[6] = g6[rr + 1];
        const float (&dn)[6] = g6[rr + 2];
        float tv[4];
        #pragma unroll
        for (int kk = 0; kk < 4; ++kk) {
            float sv = w0 * mi[kk];
            sv = fmaf(w1, dn[kk],     sv);
            sv = fmaf(w2, dn[kk + 1], sv);
            sv = fmaf(w3, dn[kk + 2], sv);
            sv = fmaf(w4, mi[kk + 2], sv);
            sv = fmaf(w5, up[kk + 2], sv);
            sv = fmaf(w6, up[kk + 1], sv);
            sv = fmaf(w7, up[kk],     sv);
            tv[kk] = 0.5f * mi[kk + 1] + 0.5f - 0.5f * sv;
            s += tv[kk];
            ss = fmaf(tv[kk], tv[kk], ss);
        }
        float4 t4 = {tv[0], tv[1], tv[2], tv[3]};
        *reinterpret_cast<float4*>(ob + (size_t)rr * W) = t4;
    }

    #pragma unroll
    for (int off = 32; off >= 1; off >>= 1) {
        s  += __shfl_down(s, off);
        ss += __shfl_down(ss, off);
    }
    __shared__ float2 wred[4];
    if (l == 0) wred[w] = make_float2(s, ss);
    __syncthreads();
    if (tid == 0) {
        float2 a0 = wred[0], a1 = wred[1], a2 = wred[2], a3 = wred[3];
        part[(size_t)b * RG + kg] = make_float2(a0.x + a1.x + a2.x + a3.x,
                                                a0.y + a1.y + a2.y + a3.y);
    }
}

__global__ __launch_bounds__(256)
void ltpe_stageB(float* __restrict__ out, const float2* __restrict__ part)
{
    const int b    = blockIdx.y;
    const int r    = blockIdx.x;
    const int tid  = threadIdx.x;
    const int lane = tid & 63;

    const float4* pp = reinterpret_cast<const float4*>(part + (size_t)b * RG);
    const float4 u = pp[tid];
    double s  = (double)u.x + (double)u.z;
    double ss = (double)u.y + (double)u.w;
    #pragma unroll
    for (int off = 32; off >= 1; off >>= 1) {
        s  += __shfl_down(s, off);
        ss += __shfl_down(ss, off);
    }
    __shared__ double red[8];
    __shared__ float2 mv;
    const int wv = tid >> 6;
    if (lane == 0) { red[wv] = s; red[4 + wv] = ss; }
    __syncthreads();
    if (tid == 0) {
        const double S  = red[0] + red[1] + red[2] + red[3];
        const double SS = red[4] + red[5] + red[6] + red[7];
        const double n    = (double)NPIX;
        const double mean = S / n;
        const double var  = SS / n - mean * mean;
        mv = make_float2((float)mean, (float)(1.0 / sqrt(var + 1e-5)));
    }
    __syncthreads();
    const float mean = mv.x, rstd = mv.y;

    const size_t base = (size_t)b * 3 * NPIX + (size_t)r * W + (tid << 2);
    const float4 t4 = *reinterpret_cast<const float4*>(out + base);
    float4 y;
    y.x = (t4.x - mean) * rstd;
    y.y = (t4.y - mean) * rstd;
    y.z = (t4.z - mean) * rstd;
    y.w = (t4.w - mean) * rstd;
    *reinterpret_cast<float4*>(out + base)            = y;
    *reinterpret_cast<float4*>(out + base + NPIX)     = y;
    *reinterpret_cast<float4*>(out + base + 2 * NPIX) = y;
}

extern "C" void kernel_launch(void* const* d_in, const int* in_sizes, int n_in,
                              void* d_out, int out_size, void* d_ws, size_t ws_size,
                              hipStream_t stream)
{
    const float* x = (const float*)d_in[0];
    float* out = (float*)d_out;
    float2* part = (float2*)d_ws;   // fused: 512 float2; fallback: 4096 float2
    unsigned* cnt = (unsigned*)((char*)d_ws + 32768);   // 8 arrival counters

    int nb = 0;
    hipError_t qe = hipOccupancyMaxActiveBlocksPerMultiprocessor(
        &nb, reinterpret_cast<const void*>(ltpe_fused), 256, 0);

    if (qe == hipSuccess && nb * 256 >= FGRID) {
        (void)hipMemsetAsync(cnt, 0, 8 * sizeof(unsigned), stream);
        void* args[] = { (void*)&x, (void*)&out, (void*)&part, (void*)&cnt };
        (void)hipLaunchCooperativeKernel((void*)ltpe_fused, dim3(FGRID), dim3(256),
                                         args, 0, stream);
    } else {
        ltpe_stage1<<<dim3(RG, B), 256, 0, stream>>>(x, out, part);
        ltpe_stageB<<<dim3(H, B), 256, 0, stream>>>(out, part);
    }
}

// Round 11
// 50.943 us; speedup vs baseline: 1.0008x; 1.0008x over previous
//
#include <hip/hip_runtime.h>
#include <math.h>

// x = (8, 3, 1024, 1024) f32, out = (8, 3, 1024, 1024) f32
constexpr int H = 1024, W = 1024, B = 8;
constexpr int NPIX = H * W;

typedef float f32x4 __attribute__((ext_vector_type(4)));   // native vec for NT stores

// ---------------- fused cooperative path ----------------
constexpr int FR    = 8;               // rows per block
constexpr int GPB   = H / FR;          // 128 row-groups (blocks) per image
constexpr int FGRID = B * GPB;         // 1024 blocks = 4/CU on 256 CUs

__device__ __forceinline__ void gload16(const float* g, float* l) {
    __builtin_amdgcn_global_load_lds(
        (const __attribute__((address_space(1))) void*)g,
        (__attribute__((address_space(3))) void*)l, 16, 0, 0);
}
__device__ __forceinline__ float grayat(const float* __restrict__ xb, int r, int c) {
    const float* p = xb + (size_t)r * W + c;
    return 0.3f * p[0] + 0.59f * p[NPIX] + 0.11f * p[2 * NPIX];
}
__device__ __forceinline__ void nt_store4(float* p, float x, float y, float z, float w) {
    f32x4 v = {x, y, z, w};
    __builtin_nontemporal_store(v, reinterpret_cast<f32x4*>(p));
}

union PackF2 { float2 f; unsigned long long u; };

// One fused kernel, TLP-oriented: 36 KB LDS -> 4 blocks/CU -> 4 waves/SIMD.
// Phase A: per-wave 3-slot LDS ring, lead-1 counted vmcnt(3) (latency hidden by
// wave switching, not per-wave lead). t in 8 float4 regs + per-block partial.
// PER-IMAGE sync via release-add arrival counter + acquire spin (coop launch
// guarantees co-residency). Phase B: butterfly-reduce 128 partials/image,
// normalize regs, write 3 replicated channels with NT stores.
__global__ __launch_bounds__(256, 4)
void ltpe_fused(const float* __restrict__ x, float* __restrict__ out,
                float2* __restrict__ part, unsigned* __restrict__ cnt)
{
    __shared__ float lds[4][3][3][256];   // wave x slot x ch x col = 36 KiB
    __shared__ float2 wred[4];

    const int blk  = blockIdx.x;
    const int b    = blk & 7;             // image pinned to XCD (round-robin dispatch)
    const int g    = blk >> 3;            // row-group 0..127
    const int r0   = g * FR;
    const int tid  = threadIdx.x;
    const int w    = tid >> 6;
    const int lane = tid & 63;
    const int c    = tid << 2;            // global column quad
    const float* xb = x + (size_t)b * 3 * NPIX;
    float (*ldsw)[3][256] = lds[w];       // this wave's private ring

    constexpr float w0 = 1.f/255.f,  w1 = 2.f/255.f,  w2 = 4.f/255.f,  w3 = 8.f/255.f,
                    w4 = 16.f/255.f, w5 = 32.f/255.f, w6 = 64.f/255.f, w7 = 128.f/255.f;

    // Prologue: edge-lane horizontal-halo gray values into registers, then DRAIN
    // vmcnt so the steady-state loop's counted waits are exact.
    float pL[FR + 2], pR[FR + 2];
    #pragma unroll
    for (int i = 0; i < FR + 2; ++i) { pL[i] = 0.f; pR[i] = 0.f; }
    if (lane == 0 && c > 0) {
        #pragma unroll
        for (int i = 0; i < FR + 2; ++i) {
            const int rr = r0 - 1 + i;
            if ((unsigned)rr < (unsigned)H) pL[i] = grayat(xb, rr, c - 1);
        }
    }
    if (lane == 63 && c + 4 < W) {
        #pragma unroll
        for (int i = 0; i < FR + 2; ++i) {
            const int rr = r0 - 1 + i;
            if ((unsigned)rr < (unsigned)H) pR[i] = grayat(xb, rr, c + 4);
        }
    }
    asm volatile("s_waitcnt vmcnt(0)" ::: "memory");
    __builtin_amdgcn_sched_barrier(0);

    // Stage row-offset `off` (row r0-1+off, CLAMPED so every block issues the
    // same gload count; garbage rows are zeroed at gray time) into ring slot.
    auto stage = [&](int off, int slot) {
        int rr = r0 - 1 + off;
        rr = rr < 0 ? 0 : (rr > H - 1 ? H - 1 : rr);
        const float* gp = xb + (size_t)rr * W + (w << 8) + (lane << 2);
        gload16(gp,            &ldsw[slot][0][0]);
        gload16(gp + NPIX,     &ldsw[slot][1][0]);
        gload16(gp + 2*NPIX,   &ldsw[slot][2][0]);
    };

    // Gray (6-wide) for row-offset `off` from ring slot.
    auto grayc = [&](int off, int slot, float (&d)[6]) {
        const bool rok = (unsigned)(r0 - 1 + off) < (unsigned)H;
        const float4 a = *reinterpret_cast<const float4*>(&ldsw[slot][0][lane << 2]);
        const float4 e = *reinterpret_cast<const float4*>(&ldsw[slot][1][lane << 2]);
        const float4 f = *reinterpret_cast<const float4*>(&ldsw[slot][2][lane << 2]);
        float g1 = 0.3f*a.x + 0.59f*e.x + 0.11f*f.x;
        float g2 = 0.3f*a.y + 0.59f*e.y + 0.11f*f.y;
        float g3 = 0.3f*a.z + 0.59f*e.z + 0.11f*f.z;
        float g4 = 0.3f*a.w + 0.59f*e.w + 0.11f*f.w;
        float glv = __shfl_up(g4, 1);
        float grv = __shfl_down(g1, 1);
        if (lane == 0)  glv = pL[off];
        if (lane == 63) grv = pR[off];
        if (!rok) { g1 = g2 = g3 = g4 = glv = grv = 0.f; }   // zero-pad row
        d[0]=glv; d[1]=g1; d[2]=g2; d[3]=g3; d[4]=g4; d[5]=grv;
    };

    float gr6[3][6];
    float4 tq[FR];                        // un-normalized t, lives in VGPRs
    float s = 0.f, ss = 0.f;

    // Pipeline prologue: offsets 0..2 staged (9 gloads); rows 0,1 resident
    // after vmcnt(3).
    stage(0, 0); stage(1, 1); stage(2, 2);
    asm volatile("s_waitcnt vmcnt(3)" ::: "memory");
    __builtin_amdgcn_sched_barrier(0);
    grayc(0, 0, gr6[0]);
    grayc(1, 1, gr6[1]);

    // Step I: issue offset I+3 (3 gloads), wait so offset I+2 is resident
    // (outstanding = offset I+3 = 3), gray(I+2), stencil output row r0+I.
#define LTPE_STEP(I, WAITSTR)                                                  \
    {                                                                          \
        if ((I) + 3 <= FR + 1) stage((I) + 3, ((I) + 3) % 3);                  \
        asm volatile(WAITSTR ::: "memory");                                    \
        __builtin_amdgcn_sched_barrier(0);                                     \
        grayc((I) + 2, ((I) + 2) % 3, gr6[((I) + 2) % 3]);                     \
        const float (&up)[6] = gr6[(I) % 3];                                   \
        const float (&mi)[6] = gr6[((I) + 1) % 3];                             \
        const float (&dn)[6] = gr6[((I) + 2) % 3];                             \
        float tv[4];                                                           \
        _Pragma("unroll")                                                      \
        for (int kk = 0; kk < 4; ++kk) {                                       \
            float sv = w0 * mi[kk];                                            \
            sv = fmaf(w1, dn[kk],     sv);                                     \
            sv = fmaf(w2, dn[kk + 1], sv);                                     \
            sv = fmaf(w3, dn[kk + 2], sv);                                     \
            sv = fmaf(w4, mi[kk + 2], sv);                                     \
            sv = fmaf(w5, up[kk + 2], sv);                                     \
            sv = fmaf(w6, up[kk + 1], sv);                                     \
            sv = fmaf(w7, up[kk],     sv);                                     \
            tv[kk] = 0.5f * mi[kk + 1] + 0.5f - 0.5f * sv;                     \
            s += tv[kk];                                                       \
            ss = fmaf(tv[kk], tv[kk], ss);                                     \
        }                                                                      \
        tq[I] = make_float4(tv[0], tv[1], tv[2], tv[3]);                       \
    }

    LTPE_STEP(0, "s_waitcnt vmcnt(3)")
    LTPE_STEP(1, "s_waitcnt vmcnt(3)")
    LTPE_STEP(2, "s_waitcnt vmcnt(3)")
    LTPE_STEP(3, "s_waitcnt vmcnt(3)")
    LTPE_STEP(4, "s_waitcnt vmcnt(3)")
    LTPE_STEP(5, "s_waitcnt vmcnt(3)")
    LTPE_STEP(6, "s_waitcnt vmcnt(3)")
    LTPE_STEP(7, "s_waitcnt vmcnt(0)")
#undef LTPE_STEP

    // Block reduce -> one fp32 partial pair per block.
    #pragma unroll
    for (int off = 32; off >= 1; off >>= 1) {
        s  += __shfl_down(s, off);
        ss += __shfl_down(ss, off);
    }
    if (lane == 0) wred[w] = make_float2(s, ss);
    __syncthreads();

    // Per-image sync: publish partial (agent-scope), release-add arrival
    // counter, tid0 acquire-spins until all GPB blocks of this image arrived.
    if (tid == 0) {
        float2 a0 = wred[0], a1 = wred[1], a2 = wred[2], a3 = wred[3];
        PackF2 pk;
        pk.f = make_float2(a0.x + a1.x + a2.x + a3.x,
                           a0.y + a1.y + a2.y + a3.y);
        __hip_atomic_store(
            reinterpret_cast<unsigned long long*>(&part[(size_t)b * GPB + g]),
            pk.u, __ATOMIC_RELAXED, __HIP_MEMORY_SCOPE_AGENT);
        __hip_atomic_fetch_add(&cnt[b], 1u, __ATOMIC_RELEASE,
                               __HIP_MEMORY_SCOPE_AGENT);
        while (__hip_atomic_load(&cnt[b], __ATOMIC_ACQUIRE,
                                 __HIP_MEMORY_SCOPE_AGENT) < (unsigned)GPB) {
            __builtin_amdgcn_s_sleep(1);
        }
    }
    __syncthreads();

    // Phase B: butterfly-reduce the image's 128 partials (2 per lane) in double.
    PackF2 p0, p1;
    p0.u = __hip_atomic_load(
        reinterpret_cast<const unsigned long long*>(&part[(size_t)b * GPB + lane]),
        __ATOMIC_RELAXED, __HIP_MEMORY_SCOPE_AGENT);
    p1.u = __hip_atomic_load(
        reinterpret_cast<const unsigned long long*>(&part[(size_t)b * GPB + 64 + lane]),
        __ATOMIC_RELAXED, __HIP_MEMORY_SCOPE_AGENT);
    double ds  = (double)p0.f.x + (double)p1.f.x;
    double dss = (double)p0.f.y + (double)p1.f.y;
    #pragma unroll
    for (int o = 1; o <= 32; o <<= 1) {
        ds  += __shfl_xor(ds, o);
        dss += __shfl_xor(dss, o);
    }
    const double n     = (double)NPIX;
    const double dmean = ds / n;
    const double dvar  = dss / n - dmean * dmean;
    const float mean = (float)dmean;
    const float rstd = (float)(1.0 / sqrt(dvar + 1e-5));

    // Non-temporal writes: out is never re-read; keep x resident in L3.
    float* ob = out + (size_t)b * 3 * NPIX + (size_t)r0 * W + c;
    #pragma unroll
    for (int i = 0; i < FR; ++i) {
        const float4 t4 = tq[i];
        const float yx = (t4.x - mean) * rstd;
        const float yy = (t4.y - mean) * rstd;
        const float yz = (t4.z - mean) * rstd;
        const float yw = (t4.w - mean) * rstd;
        float* p = ob + (size_t)i * W;
        nt_store4(p,            yx, yy, yz, yw);
        nt_store4(p + NPIX,     yx, yy, yz, yw);
        nt_store4(p + 2 * NPIX, yx, yy, yz, yw);
    }
}

// ---------------- fallback: proven round-6 two-kernel pipeline ----------------
constexpr int ROWS = 2;
constexpr int RG   = H / ROWS;          // 512

__global__ __launch_bounds__(256)
void ltpe_stage1(const float* __restrict__ x, float* __restrict__ out,
                 float2* __restrict__ part)
{
    __shared__ float lds[4][3][W];                // 48 KiB -> 3 blocks/CU
    const int b   = blockIdx.y;
    const int k   = blockIdx.x;
    const int kg  = ((k & 7) << 6) | (k >> 3);    // XCD-chunked bijective swizzle
    const int r0  = kg * ROWS;
    const int tid = threadIdx.x;
    const int w   = tid >> 6;
    const int l   = tid & 63;
    const int c   = tid << 2;
    const float* xb = x + (size_t)b * 3 * NPIX;

    #pragma unroll
    for (int s = 0; s < 4; ++s) {
        const int rr = r0 - 1 + s;
        if ((unsigned)rr < (unsigned)H) {
            #pragma unroll
            for (int ch = 0; ch < 3; ++ch) {
                const float* gp = xb + (size_t)ch * NPIX + (size_t)rr * W + (w << 8) + (l << 2);
                gload16(gp, &lds[s][ch][w << 8]);
            }
        } else {
            const float4 z = make_float4(0.f, 0.f, 0.f, 0.f);
            #pragma unroll
            for (int ch = 0; ch < 3; ++ch)
                *reinterpret_cast<float4*>(&lds[s][ch][c]) = z;
        }
    }
    __syncthreads();

    const int ql = (tid == 0)   ? 0   : tid - 1;
    const int qr = (tid == 255) ? 255 : tid + 1;
    float g6[4][6];
    #pragma unroll
    for (int s = 0; s < 4; ++s) {
        const float4 o0 = *reinterpret_cast<const float4*>(&lds[s][0][c]);
        const float4 o1 = *reinterpret_cast<const float4*>(&lds[s][1][c]);
        const float4 o2 = *reinterpret_cast<const float4*>(&lds[s][2][c]);
        const float4 l0 = *reinterpret_cast<const float4*>(&lds[s][0][ql << 2]);
        const float4 l1 = *reinterpret_cast<const float4*>(&lds[s][1][ql << 2]);
        const float4 l2 = *reinterpret_cast<const float4*>(&lds[s][2][ql << 2]);
        const float4 rq0 = *reinterpret_cast<const float4*>(&lds[s][0][qr << 2]);
        const float4 rq1 = *reinterpret_cast<const float4*>(&lds[s][1][qr << 2]);
        const float4 rq2 = *reinterpret_cast<const float4*>(&lds[s][2][qr << 2]);
        g6[s][1] = 0.3f * o0.x + 0.59f * o1.x + 0.11f * o2.x;
        g6[s][2] = 0.3f * o0.y + 0.59f * o1.y + 0.11f * o2.y;
        g6[s][3] = 0.3f * o0.z + 0.59f * o1.z + 0.11f * o2.z;
        g6[s][4] = 0.3f * o0.w + 0.59f * o1.w + 0.11f * o2.w;
        g6[s][0] = (tid == 0)   ? 0.f : 0.3f * l0.w  + 0.59f * l1.w  + 0.11f * l2.w;
        g6[s][5] = (tid == 255) ? 0.f : 0.3f * rq0.x + 0.59f * rq1.x + 0.11f * rq2.x;
    }

    constexpr float w0 = 1.f/255.f,  w1 = 2.f/255.f,  w2 = 4.f/255.f,  w3 = 8.f/255.f,
                    w4 = 16.f/255.f, w5 = 32.f/255.f, w6 = 64.f/255.f, w7 = 128.f/255.f;
    float s = 0.f, ss = 0.f;
    float* ob = out + (size_t)b * 3 * NPIX + (size_t)r0 * W + c;
    #pragma unroll
    for (int rr = 0; rr < ROWS; ++rr) {
        const float (&up)[6] = g6[rr];
        const float (&mi)[6] = g6[rr + 1];
        const float (&dn)[6] = g6[rr + 2];
        float tv[4];
        #pragma unroll
        for (int kk = 0; kk < 4; ++kk) {
            float sv = w0 * mi[kk];
            sv = fmaf(w1, dn[kk],     sv);
            sv = fmaf(w2, dn[kk + 1], sv);
            sv = fmaf(w3, dn[kk + 2], sv);
            sv = fmaf(w4, mi[kk + 2], sv);
            sv = fmaf(w5, up[kk + 2], sv);
            sv = fmaf(w6, up[kk + 1], sv);
            sv = fmaf(w7, up[kk],     sv);
            tv[kk] = 0.5f * mi[kk + 1] + 0.5f - 0.5f * sv;
            s += tv[kk];
            ss = fmaf(tv[kk], tv[kk], ss);
        }
        float4 t4 = {tv[0], tv[1], tv[2], tv[3]};
        *reinterpret_cast<float4*>(ob + (size_t)rr * W) = t4;
    }

    #pragma unroll
    for (int off = 32; off >= 1; off >>= 1) {
        s  += __shfl_down(s, off);
        ss += __shfl_down(ss, off);
    }
    __shared__ float2 wred[4];
    if (l == 0) wred[w] = make_float2(s, ss);
    __syncthreads();
    if (tid == 0) {
        float2 a0 = wred[0], a1 = wred[1], a2 = wred[2], a3 = wred[3];
        part[(size_t)b * RG + kg] = make_float2(a0.x + a1.x + a2.x + a3.x,
                                                a0.y + a1.y + a2.y + a3.y);
    }
}

__global__ __launch_bounds__(256)
void ltpe_stageB(float* __restrict__ out, const float2* __restrict__ part)
{
    const int b    = blockIdx.y;
    const int r    = blockIdx.x;
    const int tid  = threadIdx.x;
    const int lane = tid & 63;

    const float4* pp = reinterpret_cast<const float4*>(part + (size_t)b * RG);
    const float4 u = pp[tid];
    double s  = (double)u.x + (double)u.z;
    double ss = (double)u.y + (double)u.w;
    #pragma unroll
    for (int off = 32; off >= 1; off >>= 1) {
        s  += __shfl_down(s, off);
        ss += __shfl_down(ss, off);
    }
    __shared__ double red[8];
    __shared__ float2 mv;
    const int wv = tid >> 6;
    if (lane == 0) { red[wv] = s; red[4 + wv] = ss; }
    __syncthreads();
    if (tid == 0) {
        const double S  = red[0] + red[1] + red[2] + red[3];
        const double SS = red[4] + red[5] + red[6] + red[7];
        const double n    = (double)NPIX;
        const double mean = S / n;
        const double var  = SS / n - mean * mean;
        mv = make_float2((float)mean, (float)(1.0 / sqrt(var + 1e-5)));
    }
    __syncthreads();
    const float mean = mv.x, rstd = mv.y;

    const size_t base = (size_t)b * 3 * NPIX + (size_t)r * W + (tid << 2);
    const float4 t4 = *reinterpret_cast<const float4*>(out + base);
    float4 y;
    y.x = (t4.x - mean) * rstd;
    y.y = (t4.y - mean) * rstd;
    y.z = (t4.z - mean) * rstd;
    y.w = (t4.w - mean) * rstd;
    *reinterpret_cast<float4*>(out + base)            = y;
    *reinterpret_cast<float4*>(out + base + NPIX)     = y;
    *reinterpret_cast<float4*>(out + base + 2 * NPIX) = y;
}

extern "C" void kernel_launch(void* const* d_in, const int* in_sizes, int n_in,
                              void* d_out, int out_size, void* d_ws, size_t ws_size,
                              hipStream_t stream)
{
    const float* x = (const float*)d_in[0];
    float* out = (float*)d_out;
    float2* part = (float2*)d_ws;   // fused: 1024 float2; fallback: 4096 float2
    unsigned* cnt = (unsigned*)((char*)d_ws + 32768);   // 8 arrival counters

    int nb = 0;
    hipError_t qe = hipOccupancyMaxActiveBlocksPerMultiprocessor(
        &nb, reinterpret_cast<const void*>(ltpe_fused), 256, 0);

    if (qe == hipSuccess && nb * 256 >= FGRID) {
        (void)hipMemsetAsync(cnt, 0, 8 * sizeof(unsigned), stream);
        void* args[] = { (void*)&x, (void*)&out, (void*)&part, (void*)&cnt };
        (void)hipLaunchCooperativeKernel((void*)ltpe_fused, dim3(FGRID), dim3(256),
                                         args, 0, stream);
    } else {
        ltpe_stage1<<<dim3(RG, B), 256, 0, stream>>>(x, out, part);
        ltpe_stageB<<<dim3(H, B), 256, 0, stream>>>(out, part);
    }
}